// Round 13
// baseline (370.504 us; speedup 1.0000x reference)
//
#include <hip/hip_runtime.h>
#include <hip/hip_fp16.h>
#include <math.h>

#define N_NODES 50000
#define NE      800000
#define INC     128
#define F1      128     // HEADS*HID
#define HEADS   8
#define HID     16
#define OUTC    16
#define NEG     0.2f
#define NBKT    196      // (N_NODES+255)>>8
#define NPART   128      // partition blocks

union H4 { ushort4 u; __half h[4]; };
union H8 { uint4 u; __half h[8]; };

typedef _Float16 f16x8 __attribute__((ext_vector_type(8)));
typedef float    f32x4 __attribute__((ext_vector_type(4)));

// ============ CSR build: two-level counting sort (locality-friendly) ========
__global__ __launch_bounds__(256) void part_hist(const int* __restrict__ ei,
                                                 int* __restrict__ cnt) {
    __shared__ int h[NBKT];
    int tid = threadIdx.x;
    for (int i = tid; i < NBKT; i += 256) h[i] = 0;
    __syncthreads();
    for (int e = blockIdx.x * 256 + tid; e < NE; e += NPART * 256)
        atomicAdd(&h[ei[NE + e] >> 8], 1);
    __syncthreads();
    for (int i = tid; i < NBKT; i += 256) cnt[i * NPART + blockIdx.x] = h[i];
}

__global__ __launch_bounds__(1024) void scan25k(int* __restrict__ cnt) {
    __shared__ int part[1024];
    const int TOT = NBKT * NPART;             // 25088
    const int PER = (TOT + 1023) / 1024;      // 25
    int tid = threadIdx.x;
    int base = tid * PER;
    int s = 0;
    for (int i = 0; i < PER; ++i) {
        int idx = base + i;
        if (idx < TOT) s += cnt[idx];
    }
    part[tid] = s; __syncthreads();
    for (int off = 1; off < 1024; off <<= 1) {
        int t = (tid >= off) ? part[tid - off] : 0;
        __syncthreads();
        part[tid] += t;
        __syncthreads();
    }
    int run = part[tid] - s;
    for (int i = 0; i < PER; ++i) {
        int idx = base + i;
        if (idx < TOT) { int v = cnt[idx]; cnt[idx] = run; run += v; }
    }
}

// tmp packing: s in bits 0..15 (N<65536), d&255 in bits 16..23
__global__ __launch_bounds__(256) void part_scatter(const int* __restrict__ ei,
                                                    const int* __restrict__ cnt,
                                                    int* __restrict__ tmp) {
    __shared__ int cur[NBKT];
    int tid = threadIdx.x;
    for (int i = tid; i < NBKT; i += 256) cur[i] = cnt[i * NPART + blockIdx.x];
    __syncthreads();
    for (int e = blockIdx.x * 256 + tid; e < NE; e += NPART * 256) {
        int s = ei[e], d = ei[NE + e];
        int p = atomicAdd(&cur[d >> 8], 1);
        tmp[p] = s | ((d & 255) << 16);
    }
}

// bucket sort by dst&255 + fused degree histogram (64 bins) for wave packing
__global__ __launch_bounds__(256) void bucket_sort(const int* __restrict__ tmp,
                                                   const int* __restrict__ cnt,
                                                   int* __restrict__ rowstart,
                                                   int* __restrict__ csr,
                                                   int* __restrict__ dbin) {
    __shared__ int h[256];
    __shared__ int dh[64];
    int b = blockIdx.x, tid = threadIdx.x;
    int base = cnt[b * NPART];
    int end  = (b == NBKT - 1) ? NE : cnt[(b + 1) * NPART];
    h[tid] = 0;
    if (tid < 64) dh[tid] = 0;
    __syncthreads();
    for (int i = base + tid; i < end; i += 256)
        atomicAdd(&h[(tmp[i] >> 16) & 255], 1);
    __syncthreads();
    int v = h[tid];
    for (int off = 1; off < 256; off <<= 1) {
        int t = (tid >= off) ? h[tid - off] : 0;
        __syncthreads();
        h[tid] += t;
        __syncthreads();
    }
    int excl = h[tid] - v;
    int n = (b << 8) + tid;
    if (n <= N_NODES) rowstart[n] = base + excl;
    if (n < N_NODES) atomicAdd(&dh[v < 63 ? v : 63], 1);   // degree histogram
    __syncthreads();
    if (tid < 64 && dh[tid]) atomicAdd(&dbin[tid], dh[tid]);
    h[tid] = excl;
    __syncthreads();
    for (int i = base + tid; i < end; i += 256) {
        int e = tmp[i];
        int p = base + atomicAdd(&h[(e >> 16) & 255], 1);
        csr[p] = e & 0xFFFF;
    }
}

// exclusive scan of the 64 degree bins -> scatter cursors
__global__ __launch_bounds__(64) void scan64(const int* __restrict__ dbin,
                                             int* __restrict__ dcur) {
    int tid = threadIdx.x;
    int v = dbin[tid];
    int s = v;
    for (int off = 1; off < 64; off <<= 1) {
        int t = __shfl_up(s, off, 64);
        if (tid >= off) s += t;
    }
    dcur[tid] = s - v;
}

// degree-sorted node permutation (counting-sort scatter)
__global__ __launch_bounds__(256) void deg_scatter(const int* __restrict__ rowstart,
                                                   int* __restrict__ dcur,
                                                   int* __restrict__ perm) {
    int n = blockIdx.x * 256 + threadIdx.x;
    if (n >= N_NODES) return;
    int deg = rowstart[n + 1] - rowstart[n];
    int b = deg < 63 ? deg : 63;
    int pos = atomicAdd(&dcur[b], 1);
    perm[pos] = n;
}

// ------ W1 transpose to fp16 + folded attention matrix Wa ------------------
// Wa[k][col] = sum_c W1[k][h*16+c] * a[h][c],  col 0..7 = src heads, 8..15 dst
__global__ __launch_bounds__(256) void w1t_kernel(const float* __restrict__ W1,
                                                  const float* __restrict__ as1,
                                                  const float* __restrict__ ad1,
                                                  __half* __restrict__ W1t,
                                                  __half* __restrict__ waT) {
    int b = blockIdx.x;
    if (b < 64) {
        int i = b * 256 + threadIdx.x;          // 16384 elements
        int k = i >> 7, nn = i & 127;
        W1t[nn * 128 + k] = __float2half(W1[k * 128 + nn]);
    } else {
        int i = (b - 64) * 256 + threadIdx.x;   // 0..2047
        int col = i & 15, k = i >> 4;
        int h = col & 7;
        const float* av = (col < 8) ? as1 : ad1;
        float s = 0.f;
        #pragma unroll
        for (int cc = 0; cc < 16; ++cc)
            s += W1[k * 128 + h * 16 + cc] * av[h * 16 + cc];
        waT[col * 128 + k] = __float2half(s);   // B-frag layout [n=col][k]
    }
}

// ---------------- Layer 1: MFMA GEMM (x @ W1) + logits via Wa-GEMM ---------
__global__ __launch_bounds__(256) void node1_kernel(
    const float* __restrict__ x, const __half* __restrict__ W1t,
    const __half* __restrict__ waT,
    __half* __restrict__ hfeat, float* __restrict__ als, float* __restrict__ ald)
{
    __shared__ _Float16 Xh[64 * 136];    // 17.4 KB
    __shared__ _Float16 Wt[128 * 136];   // 34.8 KB (pad 8 halves/row)
    int tid = threadIdx.x;
    int n0 = blockIdx.x * 64;

    for (int idx = tid; idx < 128 * 16; idx += 256) {   // 16 x uint4 per row
        int row = idx >> 4, c8 = (idx & 15) * 8;
        *(uint4*)(&Wt[row * 136 + c8]) = ((const uint4*)W1t)[idx];
    }
    for (int idx = tid; idx < 64 * 32; idx += 256) {
        int m = idx >> 5, f4 = idx & 31;
        int n = n0 + m;
        float4 v = (n < N_NODES) ? ((const float4*)(x + (size_t)n * INC))[f4]
                                 : make_float4(0.f, 0.f, 0.f, 0.f);
        union { unsigned long long u; _Float16 h[4]; } p;
        p.h[0] = (_Float16)v.x; p.h[1] = (_Float16)v.y;
        p.h[2] = (_Float16)v.z; p.h[3] = (_Float16)v.w;
        *(unsigned long long*)(&Xh[m * 136 + f4 * 4]) = p.u;
    }
    __syncthreads();

    int wave = tid >> 6, lane = tid & 63;
    int colL = lane & 15, q = lane >> 4;
    int nb = wave * 32;

    f32x4 acc[4][2];
    #pragma unroll
    for (int mt = 0; mt < 4; ++mt)
        #pragma unroll
        for (int nt = 0; nt < 2; ++nt)
            acc[mt][nt] = (f32x4){0.f, 0.f, 0.f, 0.f};
    f32x4 acc2 = (f32x4){0.f, 0.f, 0.f, 0.f};   // logits, mt = wave

    #pragma unroll
    for (int kb = 0; kb < 4; ++kb) {
        int ko = kb * 32 + q * 8;
        f16x8 b0 = *(const f16x8*)(&Wt[(nb +  0 + colL) * 136 + ko]);
        f16x8 b1 = *(const f16x8*)(&Wt[(nb + 16 + colL) * 136 + ko]);
        #pragma unroll
        for (int mt = 0; mt < 4; ++mt) {
            f16x8 a = *(const f16x8*)(&Xh[(mt * 16 + colL) * 136 + ko]);
            acc[mt][0] = __builtin_amdgcn_mfma_f32_16x16x32_f16(a, b0, acc[mt][0], 0, 0, 0);
            acc[mt][1] = __builtin_amdgcn_mfma_f32_16x16x32_f16(a, b1, acc[mt][1], 0, 0, 0);
        }
        f16x8 bw = *(const f16x8*)(waT + colL * 128 + ko);           // global, L2-hot
        f16x8 aw = *(const f16x8*)(&Xh[(wave * 16 + colL) * 136 + ko]);
        acc2 = __builtin_amdgcn_mfma_f32_16x16x32_f16(aw, bw, acc2, 0, 0, 0);
    }

    // h stores (fp16)
    #pragma unroll
    for (int nt = 0; nt < 2; ++nt) {
        int col = nb + nt * 16 + colL;
        #pragma unroll
        for (int mt = 0; mt < 4; ++mt) {
            f32x4 d = acc[mt][nt];
            #pragma unroll
            for (int r = 0; r < 4; ++r) {
                int node = n0 + mt * 16 + q * 4 + r;
                if (node < N_NODES) hfeat[(size_t)node * F1 + col] = __float2half(d[r]);
            }
        }
    }
    // logit stores: split src/dst arrays (32B/node granularity for the gather)
    #pragma unroll
    for (int r = 0; r < 4; ++r) {
        int node = n0 + wave * 16 + q * 4 + r;
        if (node < N_NODES) {
            if (colL < 8) als[node * 8 + colL] = acc2[r];
            else          ald[node * 8 + (colL - 8)] = acc2[r];
        }
    }
}

// ------ Layer 1 gather: degree-packed waves, depth-2 static pipeline -------
__global__ __launch_bounds__(256) void agg1_kernel(
    const int* __restrict__ rowstart, const int* __restrict__ csr,
    const int* __restrict__ perm,
    const __half* __restrict__ h1, const float* __restrict__ als,
    const float* __restrict__ ald, const float* __restrict__ b1,
    __half* __restrict__ hout)
{
    int tid = threadIdx.x;
    int n = perm[blockIdx.x * 16 + (tid >> 4)];   // degree-sorted order
    int lane = tid & 15;
    int c = lane * 8;
    int head = lane >> 1;
    float aldn = ald[n * 8 + head];
    float v0 = als[n * 8 + head] + aldn;
    v0 = fmaxf(v0, NEG * v0);
    float w0 = __expf(v0);
    float sum = w0;
    float a[8];
    {
        H8 hs; hs.u = *(const uint4*)(h1 + (size_t)n * F1 + c);
        #pragma unroll
        for (int i = 0; i < 8; ++i) a[i] = w0 * __half2float(hs.h[i]);
    }
    int r0 = rowstart[n], r1 = rowstart[n + 1];

    float vA = 0.f, vB = 0.f;
    H8 hA, hB; hA.u = make_uint4(0,0,0,0); hB.u = hA.u;
    int sC = 0, sD = 0;
    if (r0 < r1) {
        int s = csr[r0];
        float t = als[s * 8 + head] + aldn;
        vA = fmaxf(t, NEG * t);
        hA.u = *(const uint4*)(h1 + (size_t)s * F1 + c);
    }
    if (r0 + 1 < r1) {
        int s = csr[r0 + 1];
        float t = als[s * 8 + head] + aldn;
        vB = fmaxf(t, NEG * t);
        hB.u = *(const uint4*)(h1 + (size_t)s * F1 + c);
    }
    if (r0 + 2 < r1) sC = csr[r0 + 2];
    if (r0 + 3 < r1) sD = csr[r0 + 3];

    int k = r0;
    for (; k + 1 < r1; k += 2) {
        float vcA = vA, vcB = vB;
        H8 hcA = hA, hcB = hB;
        int sE = (k + 4 < r1) ? csr[k + 4] : 0;
        int sF = (k + 5 < r1) ? csr[k + 5] : 0;
        if (k + 2 < r1) {
            float t = als[sC * 8 + head] + aldn;
            vA = fmaxf(t, NEG * t);
            hA.u = *(const uint4*)(h1 + (size_t)sC * F1 + c);
        }
        if (k + 3 < r1) {
            float t = als[sD * 8 + head] + aldn;
            vB = fmaxf(t, NEG * t);
            hB.u = *(const uint4*)(h1 + (size_t)sD * F1 + c);
        }
        sC = sE; sD = sF;
        float wA = __expf(vcA), wB = __expf(vcB);
        sum += wA + wB;
        #pragma unroll
        for (int i = 0; i < 8; ++i) {
            a[i] = fmaf(wA, __half2float(hcA.h[i]), a[i]);
            a[i] = fmaf(wB, __half2float(hcB.h[i]), a[i]);
        }
    }
    if (k < r1) {                      // odd tail: consume slot A
        float wA = __expf(vA);
        sum += wA;
        #pragma unroll
        for (int i = 0; i < 8; ++i) a[i] = fmaf(wA, __half2float(hA.h[i]), a[i]);
    }

    float inv = 1.0f / sum;
    H8 t;
    #pragma unroll
    for (int i = 0; i < 8; ++i) {
        float o = a[i] * inv + b1[c + i];
        o = o > 0.f ? o : (__expf(o) - 1.0f);
        t.h[i] = __float2half(o);
    }
    *(uint4*)(hout + (size_t)n * F1 + c) = t.u;
}

// ---------------- Layer 2: GEMM (h1' @ W2) + logits, fp16 in/out ----------
__global__ __launch_bounds__(256) void node2_kernel(
    const __half* __restrict__ h1, const float* __restrict__ W2,
    const float* __restrict__ a_s, const float* __restrict__ a_d,
    __half* __restrict__ h2, float* __restrict__ als2, float* __restrict__ ald2)
{
    __shared__ float W2l[F1 * OUTC];   // 8 KB
    for (int i = threadIdx.x; i < F1 * OUTC; i += 256) W2l[i] = W2[i];
    __syncthreads();
    int n = blockIdx.x * blockDim.x + threadIdx.x;
    if (n >= N_NODES) return;

    float o[OUTC];
    #pragma unroll
    for (int c = 0; c < OUTC; ++c) o[c] = 0.f;
    const uint4* xr = (const uint4*)(h1 + (size_t)n * F1);
    for (int k8 = 0; k8 < 16; ++k8) {
        H8 xv; xv.u = xr[k8];
        int k = k8 * 8;
        #pragma unroll
        for (int j = 0; j < 8; ++j) {
            float xf = __half2float(xv.h[j]);
            #pragma unroll
            for (int c = 0; c < OUTC; ++c)
                o[c] = fmaf(xf, W2l[(k + j) * OUTC + c], o[c]);
        }
    }
    H8 s0, s1;
    #pragma unroll
    for (int j = 0; j < 8; ++j) { s0.h[j] = __float2half(o[j]); s1.h[j] = __float2half(o[8 + j]); }
    uint4* h2o = (uint4*)(h2 + (size_t)n * OUTC);
    h2o[0] = s0.u; h2o[1] = s1.u;
    float ps = 0.f, pd = 0.f;
    #pragma unroll
    for (int c = 0; c < OUTC; ++c) { ps += o[c] * a_s[c]; pd += o[c] * a_d[c]; }
    als2[n] = ps; ald2[n] = pd;
}

// ------ Layer 2 gather: degree-packed waves, depth-2 static pipeline -------
__global__ __launch_bounds__(256) void agg2_kernel(
    const int* __restrict__ rowstart, const int* __restrict__ csr,
    const int* __restrict__ perm,
    const __half* __restrict__ h2, const float* __restrict__ als,
    const float* __restrict__ ald, const float* __restrict__ b2,
    float* __restrict__ out)
{
    int tid = threadIdx.x;
    int idx = blockIdx.x * 64 + (tid >> 2);
    if (idx >= N_NODES) return;
    int n = perm[idx];
    int c = (tid & 3) * 4;
    float aldn = ald[n];
    float v0 = als[n] + aldn;
    v0 = fmaxf(v0, NEG * v0);
    float w0 = __expf(v0);
    float sum = w0;
    H4 hs; hs.u = *(const ushort4*)(h2 + (size_t)n * OUTC + c);
    float a0 = w0 * __half2float(hs.h[0]), a1 = w0 * __half2float(hs.h[1]);
    float a2 = w0 * __half2float(hs.h[2]), a3 = w0 * __half2float(hs.h[3]);
    int r0 = rowstart[n], r1 = rowstart[n + 1];

    float vA = 0.f, vB = 0.f;
    H4 hA, hB; hA.u = make_ushort4(0,0,0,0); hB.u = hA.u;
    int sC = 0, sD = 0;
    if (r0 < r1) {
        int s = csr[r0];
        float t = als[s] + aldn;
        vA = fmaxf(t, NEG * t);
        hA.u = *(const ushort4*)(h2 + (size_t)s * OUTC + c);
    }
    if (r0 + 1 < r1) {
        int s = csr[r0 + 1];
        float t = als[s] + aldn;
        vB = fmaxf(t, NEG * t);
        hB.u = *(const ushort4*)(h2 + (size_t)s * OUTC + c);
    }
    if (r0 + 2 < r1) sC = csr[r0 + 2];
    if (r0 + 3 < r1) sD = csr[r0 + 3];

    int k = r0;
    for (; k + 1 < r1; k += 2) {
        float vcA = vA, vcB = vB;
        H4 hcA = hA, hcB = hB;
        int sE = (k + 4 < r1) ? csr[k + 4] : 0;
        int sF = (k + 5 < r1) ? csr[k + 5] : 0;
        if (k + 2 < r1) {
            float t = als[sC] + aldn;
            vA = fmaxf(t, NEG * t);
            hA.u = *(const ushort4*)(h2 + (size_t)sC * OUTC + c);
        }
        if (k + 3 < r1) {
            float t = als[sD] + aldn;
            vB = fmaxf(t, NEG * t);
            hB.u = *(const ushort4*)(h2 + (size_t)sD * OUTC + c);
        }
        sC = sE; sD = sF;
        float wA = __expf(vcA), wB = __expf(vcB);
        sum += wA + wB;
        a0 = fmaf(wA, __half2float(hcA.h[0]), a0); a0 = fmaf(wB, __half2float(hcB.h[0]), a0);
        a1 = fmaf(wA, __half2float(hcA.h[1]), a1); a1 = fmaf(wB, __half2float(hcB.h[1]), a1);
        a2 = fmaf(wA, __half2float(hcA.h[2]), a2); a2 = fmaf(wB, __half2float(hcB.h[2]), a2);
        a3 = fmaf(wA, __half2float(hcA.h[3]), a3); a3 = fmaf(wB, __half2float(hcB.h[3]), a3);
    }
    if (k < r1) {
        float wA = __expf(vA);
        sum += wA;
        a0 = fmaf(wA, __half2float(hA.h[0]), a0);
        a1 = fmaf(wA, __half2float(hA.h[1]), a1);
        a2 = fmaf(wA, __half2float(hA.h[2]), a2);
        a3 = fmaf(wA, __half2float(hA.h[3]), a3);
    }

    float inv = 1.0f / sum;
    float4 bv = *(const float4*)(b2 + c);
    float4 o;
    o.x = a0 * inv + bv.x; o.y = a1 * inv + bv.y;
    o.z = a2 * inv + bv.z; o.w = a3 * inv + bv.w;
    *(float4*)(out + (size_t)n * OUTC + c) = o;
}

extern "C" void kernel_launch(void* const* d_in, const int* in_sizes, int n_in,
                              void* d_out, int out_size, void* d_ws, size_t ws_size,
                              hipStream_t stream)
{
    const float* x   = (const float*)d_in[0];
    const int*   ei  = (const int*)  d_in[1];
    const float* W1  = (const float*)d_in[2];
    const float* as1 = (const float*)d_in[3];
    const float* ad1 = (const float*)d_in[4];
    const float* b1  = (const float*)d_in[5];
    const float* W2  = (const float*)d_in[6];
    const float* as2 = (const float*)d_in[7];
    const float* ad2 = (const float*)d_in[8];
    const float* b2  = (const float*)d_in[9];
    float* out = (float*)d_out;

    char* wsb = (char*)d_ws;
    const size_t SZ_H1 = (size_t)N_NODES * F1 * sizeof(__half);   // 12.8 MB
    __half* h1h = (__half*)wsb;
    __half* h1b = (__half*)(wsb + SZ_H1);
    float*  als1 = (float*)(wsb + 2 * SZ_H1);                     // N*8
    float*  ald1 = als1 + (size_t)N_NODES * 8;                    // N*8
    __half* h2f  = (__half*)(ald1 + (size_t)N_NODES * 8);         // N*16 fp16
    float*  als2 = (float*)(h2f + (size_t)N_NODES * OUTC);        // N
    float*  ald2 = als2 + N_NODES;                                // N
    __half* w1t  = (__half*)(ald2 + N_NODES);                     // 128*128 fp16
    __half* waT  = w1t + INC * F1;                                // 16*128 fp16
    int*    tmp  = (int*)(waT + 16 * INC);                        // NE ints (packed)
    int*    cnt  = tmp + NE;                                      // NBKT*NPART
    int*    csr  = cnt + NBKT * NPART;                            // NE
    int*    rowstart = csr + NE;                                  // N+1
    int*    dbin = rowstart + N_NODES + 1;                        // 64
    int*    dcur = dbin + 64;                                     // 64
    int*    perm = dcur + 64;                                     // N

    // ---- CSR build + weight prep + degree-sorted permutation ----
    hipMemsetAsync(dbin, 0, 64 * sizeof(int), stream);
    part_hist   <<<NPART, 256, 0, stream>>>(ei, cnt);
    w1t_kernel  <<<72, 256, 0, stream>>>(W1, as1, ad1, w1t, waT);
    scan25k     <<<1, 1024, 0, stream>>>(cnt);
    part_scatter<<<NPART, 256, 0, stream>>>(ei, cnt, tmp);
    bucket_sort <<<NBKT, 256, 0, stream>>>(tmp, cnt, rowstart, csr, dbin);
    scan64      <<<1, 64, 0, stream>>>(dbin, dcur);
    deg_scatter <<<(N_NODES + 255) / 256, 256, 0, stream>>>(rowstart, dcur, perm);

    // ---- layer 1 ----
    node1_kernel<<<(N_NODES + 63) / 64, 256, 0, stream>>>(x, w1t, waT, h1h, als1, ald1);
    agg1_kernel<<<N_NODES / 16, 256, 0, stream>>>(rowstart, csr, perm, h1h, als1, ald1, b1, h1b);

    // ---- layer 2 ----
    node2_kernel<<<(N_NODES + 255) / 256, 256, 0, stream>>>(h1b, W2, as2, ad2, h2f, als2, ald2);
    agg2_kernel<<<(N_NODES + 63) / 64, 256, 0, stream>>>(rowstart, csr, perm, h2f, als2, ald2, b2, out);
}

// Round 14
// 256.107 us; speedup vs baseline: 1.4467x; 1.4467x over previous
//
#include <hip/hip_runtime.h>
#include <hip/hip_fp16.h>
#include <math.h>

#define N_NODES 50000
#define NE      800000
#define INC     128
#define F1      128     // HEADS*HID
#define HEADS   8
#define HID     16
#define OUTC    16
#define NEG     0.2f
#define NBKT    196      // (N_NODES+255)>>8
#define NPART   128      // partition blocks

union H4 { ushort4 u; __half h[4]; };
union H8 { uint4 u; __half h[8]; };

typedef _Float16 f16x8 __attribute__((ext_vector_type(8)));
typedef float    f32x4 __attribute__((ext_vector_type(4)));

// ============ CSR build: two-level counting sort (locality-friendly) ========
__global__ __launch_bounds__(256) void part_hist(const int* __restrict__ ei,
                                                 int* __restrict__ cnt) {
    __shared__ int h[NBKT];
    int tid = threadIdx.x;
    for (int i = tid; i < NBKT; i += 256) h[i] = 0;
    __syncthreads();
    for (int e = blockIdx.x * 256 + tid; e < NE; e += NPART * 256)
        atomicAdd(&h[ei[NE + e] >> 8], 1);
    __syncthreads();
    for (int i = tid; i < NBKT; i += 256) cnt[i * NPART + blockIdx.x] = h[i];
}

__global__ __launch_bounds__(1024) void scan25k(int* __restrict__ cnt) {
    __shared__ int part[1024];
    const int TOT = NBKT * NPART;             // 25088
    const int PER = (TOT + 1023) / 1024;      // 25
    int tid = threadIdx.x;
    int base = tid * PER;
    int s = 0;
    for (int i = 0; i < PER; ++i) {
        int idx = base + i;
        if (idx < TOT) s += cnt[idx];
    }
    part[tid] = s; __syncthreads();
    for (int off = 1; off < 1024; off <<= 1) {
        int t = (tid >= off) ? part[tid - off] : 0;
        __syncthreads();
        part[tid] += t;
        __syncthreads();
    }
    int run = part[tid] - s;
    for (int i = 0; i < PER; ++i) {
        int idx = base + i;
        if (idx < TOT) { int v = cnt[idx]; cnt[idx] = run; run += v; }
    }
}

// tmp packing: s in bits 0..15 (N<65536), d&255 in bits 16..23
__global__ __launch_bounds__(256) void part_scatter(const int* __restrict__ ei,
                                                    const int* __restrict__ cnt,
                                                    int* __restrict__ tmp) {
    __shared__ int cur[NBKT];
    int tid = threadIdx.x;
    for (int i = tid; i < NBKT; i += 256) cur[i] = cnt[i * NPART + blockIdx.x];
    __syncthreads();
    for (int e = blockIdx.x * 256 + tid; e < NE; e += NPART * 256) {
        int s = ei[e], d = ei[NE + e];
        int p = atomicAdd(&cur[d >> 8], 1);
        tmp[p] = s | ((d & 255) << 16);
    }
}

// bucket sort by dst&255; also emit per-block degree histogram dcnt[bin][blk]
__global__ __launch_bounds__(256) void bucket_sort(const int* __restrict__ tmp,
                                                   const int* __restrict__ cnt,
                                                   int* __restrict__ rowstart,
                                                   int* __restrict__ csr,
                                                   int* __restrict__ dcnt) {
    __shared__ int h[256];
    __shared__ int dh[64];
    int b = blockIdx.x, tid = threadIdx.x;
    int base = cnt[b * NPART];
    int end  = (b == NBKT - 1) ? NE : cnt[(b + 1) * NPART];
    h[tid] = 0;
    if (tid < 64) dh[tid] = 0;
    __syncthreads();
    for (int i = base + tid; i < end; i += 256)
        atomicAdd(&h[(tmp[i] >> 16) & 255], 1);
    __syncthreads();
    int v = h[tid];
    for (int off = 1; off < 256; off <<= 1) {
        int t = (tid >= off) ? h[tid - off] : 0;
        __syncthreads();
        h[tid] += t;
        __syncthreads();
    }
    int excl = h[tid] - v;
    int n = (b << 8) + tid;
    if (n <= N_NODES) rowstart[n] = base + excl;
    if (n < N_NODES) atomicAdd(&dh[v < 63 ? v : 63], 1);   // LDS degree histogram
    __syncthreads();
    if (tid < 64) dcnt[tid * NBKT + b] = dh[tid];          // bin-major
    h[tid] = excl;
    __syncthreads();
    for (int i = base + tid; i < end; i += 256) {
        int e = tmp[i];
        int p = base + atomicAdd(&h[(e >> 16) & 255], 1);
        csr[p] = e & 0xFFFF;
    }
}

// exclusive scan of dcnt (64*NBKT = 12544 ints, bin-major = perm order)
__global__ __launch_bounds__(1024) void scan12k(int* __restrict__ dcnt) {
    __shared__ int part[1024];
    const int TOT = 64 * NBKT;                // 12544
    const int PER = (TOT + 1023) / 1024;      // 13
    int tid = threadIdx.x;
    int base = tid * PER;
    int s = 0;
    for (int i = 0; i < PER; ++i) {
        int idx = base + i;
        if (idx < TOT) s += dcnt[idx];
    }
    part[tid] = s; __syncthreads();
    for (int off = 1; off < 1024; off <<= 1) {
        int t = (tid >= off) ? part[tid - off] : 0;
        __syncthreads();
        part[tid] += t;
        __syncthreads();
    }
    int run = part[tid] - s;
    for (int i = 0; i < PER; ++i) {
        int idx = base + i;
        if (idx < TOT) { int v = dcnt[idx]; dcnt[idx] = run; run += v; }
    }
}

// degree-sorted node permutation; LDS cursors only (no global atomics)
__global__ __launch_bounds__(256) void dscatter(const int* __restrict__ rowstart,
                                                const int* __restrict__ dcnt,
                                                int* __restrict__ perm) {
    __shared__ int cur[64];
    int b = blockIdx.x, tid = threadIdx.x;
    if (tid < 64) cur[tid] = dcnt[tid * NBKT + b];
    __syncthreads();
    int n = b * 256 + tid;
    if (n < N_NODES) {
        int deg = rowstart[n + 1] - rowstart[n];
        int bin = deg < 63 ? deg : 63;
        int pos = atomicAdd(&cur[bin], 1);
        perm[pos] = n;
    }
}

// ------ W1 transpose to fp16 + folded attention matrix Wa ------------------
__global__ __launch_bounds__(256) void w1t_kernel(const float* __restrict__ W1,
                                                  const float* __restrict__ as1,
                                                  const float* __restrict__ ad1,
                                                  __half* __restrict__ W1t,
                                                  __half* __restrict__ waT) {
    int b = blockIdx.x;
    if (b < 64) {
        int i = b * 256 + threadIdx.x;          // 16384 elements
        int k = i >> 7, nn = i & 127;
        W1t[nn * 128 + k] = __float2half(W1[k * 128 + nn]);
    } else {
        int i = (b - 64) * 256 + threadIdx.x;   // 0..2047
        int col = i & 15, k = i >> 4;
        int h = col & 7;
        const float* av = (col < 8) ? as1 : ad1;
        float s = 0.f;
        #pragma unroll
        for (int cc = 0; cc < 16; ++cc)
            s += W1[k * 128 + h * 16 + cc] * av[h * 16 + cc];
        waT[col * 128 + k] = __float2half(s);   // B-frag layout [n=col][k]
    }
}

// ---------------- Layer 1: MFMA GEMM (x @ W1) + logits via Wa-GEMM ---------
__global__ __launch_bounds__(256) void node1_kernel(
    const float* __restrict__ x, const __half* __restrict__ W1t,
    const __half* __restrict__ waT,
    __half* __restrict__ hfeat, float* __restrict__ als, float* __restrict__ ald)
{
    __shared__ _Float16 Xh[64 * 136];    // 17.4 KB
    __shared__ _Float16 Wt[128 * 136];   // 34.8 KB (pad 8 halves/row)
    int tid = threadIdx.x;
    int n0 = blockIdx.x * 64;

    for (int idx = tid; idx < 128 * 16; idx += 256) {   // 16 x uint4 per row
        int row = idx >> 4, c8 = (idx & 15) * 8;
        *(uint4*)(&Wt[row * 136 + c8]) = ((const uint4*)W1t)[idx];
    }
    for (int idx = tid; idx < 64 * 32; idx += 256) {
        int m = idx >> 5, f4 = idx & 31;
        int n = n0 + m;
        float4 v = (n < N_NODES) ? ((const float4*)(x + (size_t)n * INC))[f4]
                                 : make_float4(0.f, 0.f, 0.f, 0.f);
        union { unsigned long long u; _Float16 h[4]; } p;
        p.h[0] = (_Float16)v.x; p.h[1] = (_Float16)v.y;
        p.h[2] = (_Float16)v.z; p.h[3] = (_Float16)v.w;
        *(unsigned long long*)(&Xh[m * 136 + f4 * 4]) = p.u;
    }
    __syncthreads();

    int wave = tid >> 6, lane = tid & 63;
    int colL = lane & 15, q = lane >> 4;
    int nb = wave * 32;

    f32x4 acc[4][2];
    #pragma unroll
    for (int mt = 0; mt < 4; ++mt)
        #pragma unroll
        for (int nt = 0; nt < 2; ++nt)
            acc[mt][nt] = (f32x4){0.f, 0.f, 0.f, 0.f};
    f32x4 acc2 = (f32x4){0.f, 0.f, 0.f, 0.f};   // logits, mt = wave

    #pragma unroll
    for (int kb = 0; kb < 4; ++kb) {
        int ko = kb * 32 + q * 8;
        f16x8 b0 = *(const f16x8*)(&Wt[(nb +  0 + colL) * 136 + ko]);
        f16x8 b1 = *(const f16x8*)(&Wt[(nb + 16 + colL) * 136 + ko]);
        #pragma unroll
        for (int mt = 0; mt < 4; ++mt) {
            f16x8 a = *(const f16x8*)(&Xh[(mt * 16 + colL) * 136 + ko]);
            acc[mt][0] = __builtin_amdgcn_mfma_f32_16x16x32_f16(a, b0, acc[mt][0], 0, 0, 0);
            acc[mt][1] = __builtin_amdgcn_mfma_f32_16x16x32_f16(a, b1, acc[mt][1], 0, 0, 0);
        }
        f16x8 bw = *(const f16x8*)(waT + colL * 128 + ko);           // global, L2-hot
        f16x8 aw = *(const f16x8*)(&Xh[(wave * 16 + colL) * 136 + ko]);
        acc2 = __builtin_amdgcn_mfma_f32_16x16x32_f16(aw, bw, acc2, 0, 0, 0);
    }

    // h stores (fp16)
    #pragma unroll
    for (int nt = 0; nt < 2; ++nt) {
        int col = nb + nt * 16 + colL;
        #pragma unroll
        for (int mt = 0; mt < 4; ++mt) {
            f32x4 d = acc[mt][nt];
            #pragma unroll
            for (int r = 0; r < 4; ++r) {
                int node = n0 + mt * 16 + q * 4 + r;
                if (node < N_NODES) hfeat[(size_t)node * F1 + col] = __float2half(d[r]);
            }
        }
    }
    // logit stores: split src/dst arrays (32B/node granularity for the gather)
    #pragma unroll
    for (int r = 0; r < 4; ++r) {
        int node = n0 + wave * 16 + q * 4 + r;
        if (node < N_NODES) {
            if (colL < 8) als[node * 8 + colL] = acc2[r];
            else          ald[node * 8 + (colL - 8)] = acc2[r];
        }
    }
}

// ------ Layer 1 gather: degree-packed waves, depth-2 static pipeline -------
__global__ __launch_bounds__(256) void agg1_kernel(
    const int* __restrict__ rowstart, const int* __restrict__ csr,
    const int* __restrict__ perm,
    const __half* __restrict__ h1, const float* __restrict__ als,
    const float* __restrict__ ald, const float* __restrict__ b1,
    __half* __restrict__ hout)
{
    int tid = threadIdx.x;
    int n = perm[blockIdx.x * 16 + (tid >> 4)];   // degree-sorted order
    int lane = tid & 15;
    int c = lane * 8;
    int head = lane >> 1;
    float aldn = ald[n * 8 + head];
    float v0 = als[n * 8 + head] + aldn;
    v0 = fmaxf(v0, NEG * v0);
    float w0 = __expf(v0);
    float sum = w0;
    float a[8];
    {
        H8 hs; hs.u = *(const uint4*)(h1 + (size_t)n * F1 + c);
        #pragma unroll
        for (int i = 0; i < 8; ++i) a[i] = w0 * __half2float(hs.h[i]);
    }
    int r0 = rowstart[n], r1 = rowstart[n + 1];

    float vA = 0.f, vB = 0.f;
    H8 hA, hB; hA.u = make_uint4(0,0,0,0); hB.u = hA.u;
    int sC = 0, sD = 0;
    if (r0 < r1) {
        int s = csr[r0];
        float t = als[s * 8 + head] + aldn;
        vA = fmaxf(t, NEG * t);
        hA.u = *(const uint4*)(h1 + (size_t)s * F1 + c);
    }
    if (r0 + 1 < r1) {
        int s = csr[r0 + 1];
        float t = als[s * 8 + head] + aldn;
        vB = fmaxf(t, NEG * t);
        hB.u = *(const uint4*)(h1 + (size_t)s * F1 + c);
    }
    if (r0 + 2 < r1) sC = csr[r0 + 2];
    if (r0 + 3 < r1) sD = csr[r0 + 3];

    int k = r0;
    for (; k + 1 < r1; k += 2) {
        float vcA = vA, vcB = vB;
        H8 hcA = hA, hcB = hB;
        int sE = (k + 4 < r1) ? csr[k + 4] : 0;
        int sF = (k + 5 < r1) ? csr[k + 5] : 0;
        if (k + 2 < r1) {
            float t = als[sC * 8 + head] + aldn;
            vA = fmaxf(t, NEG * t);
            hA.u = *(const uint4*)(h1 + (size_t)sC * F1 + c);
        }
        if (k + 3 < r1) {
            float t = als[sD * 8 + head] + aldn;
            vB = fmaxf(t, NEG * t);
            hB.u = *(const uint4*)(h1 + (size_t)sD * F1 + c);
        }
        sC = sE; sD = sF;
        float wA = __expf(vcA), wB = __expf(vcB);
        sum += wA + wB;
        #pragma unroll
        for (int i = 0; i < 8; ++i) {
            a[i] = fmaf(wA, __half2float(hcA.h[i]), a[i]);
            a[i] = fmaf(wB, __half2float(hcB.h[i]), a[i]);
        }
    }
    if (k < r1) {                      // odd tail: consume slot A
        float wA = __expf(vA);
        sum += wA;
        #pragma unroll
        for (int i = 0; i < 8; ++i) a[i] = fmaf(wA, __half2float(hA.h[i]), a[i]);
    }

    float inv = 1.0f / sum;
    H8 t;
    #pragma unroll
    for (int i = 0; i < 8; ++i) {
        float o = a[i] * inv + b1[c + i];
        o = o > 0.f ? o : (__expf(o) - 1.0f);
        t.h[i] = __float2half(o);
    }
    *(uint4*)(hout + (size_t)n * F1 + c) = t.u;
}

// ---------------- Layer 2: GEMM (h1' @ W2) + logits, fp16 in/out ----------
__global__ __launch_bounds__(256) void node2_kernel(
    const __half* __restrict__ h1, const float* __restrict__ W2,
    const float* __restrict__ a_s, const float* __restrict__ a_d,
    __half* __restrict__ h2, float* __restrict__ als2, float* __restrict__ ald2)
{
    __shared__ float W2l[F1 * OUTC];   // 8 KB
    for (int i = threadIdx.x; i < F1 * OUTC; i += 256) W2l[i] = W2[i];
    __syncthreads();
    int n = blockIdx.x * blockDim.x + threadIdx.x;
    if (n >= N_NODES) return;

    float o[OUTC];
    #pragma unroll
    for (int c = 0; c < OUTC; ++c) o[c] = 0.f;
    const uint4* xr = (const uint4*)(h1 + (size_t)n * F1);
    for (int k8 = 0; k8 < 16; ++k8) {
        H8 xv; xv.u = xr[k8];
        int k = k8 * 8;
        #pragma unroll
        for (int j = 0; j < 8; ++j) {
            float xf = __half2float(xv.h[j]);
            #pragma unroll
            for (int c = 0; c < OUTC; ++c)
                o[c] = fmaf(xf, W2l[(k + j) * OUTC + c], o[c]);
        }
    }
    H8 s0, s1;
    #pragma unroll
    for (int j = 0; j < 8; ++j) { s0.h[j] = __float2half(o[j]); s1.h[j] = __float2half(o[8 + j]); }
    uint4* h2o = (uint4*)(h2 + (size_t)n * OUTC);
    h2o[0] = s0.u; h2o[1] = s1.u;
    float ps = 0.f, pd = 0.f;
    #pragma unroll
    for (int c = 0; c < OUTC; ++c) { ps += o[c] * a_s[c]; pd += o[c] * a_d[c]; }
    als2[n] = ps; ald2[n] = pd;
}

// ------ Layer 2 gather: degree-packed waves, depth-2 static pipeline -------
__global__ __launch_bounds__(256) void agg2_kernel(
    const int* __restrict__ rowstart, const int* __restrict__ csr,
    const int* __restrict__ perm,
    const __half* __restrict__ h2, const float* __restrict__ als,
    const float* __restrict__ ald, const float* __restrict__ b2,
    float* __restrict__ out)
{
    int tid = threadIdx.x;
    int idx = blockIdx.x * 64 + (tid >> 2);
    if (idx >= N_NODES) return;
    int n = perm[idx];
    int c = (tid & 3) * 4;
    float aldn = ald[n];
    float v0 = als[n] + aldn;
    v0 = fmaxf(v0, NEG * v0);
    float w0 = __expf(v0);
    float sum = w0;
    H4 hs; hs.u = *(const ushort4*)(h2 + (size_t)n * OUTC + c);
    float a0 = w0 * __half2float(hs.h[0]), a1 = w0 * __half2float(hs.h[1]);
    float a2 = w0 * __half2float(hs.h[2]), a3 = w0 * __half2float(hs.h[3]);
    int r0 = rowstart[n], r1 = rowstart[n + 1];

    float vA = 0.f, vB = 0.f;
    H4 hA, hB; hA.u = make_ushort4(0,0,0,0); hB.u = hA.u;
    int sC = 0, sD = 0;
    if (r0 < r1) {
        int s = csr[r0];
        float t = als[s] + aldn;
        vA = fmaxf(t, NEG * t);
        hA.u = *(const ushort4*)(h2 + (size_t)s * OUTC + c);
    }
    if (r0 + 1 < r1) {
        int s = csr[r0 + 1];
        float t = als[s] + aldn;
        vB = fmaxf(t, NEG * t);
        hB.u = *(const ushort4*)(h2 + (size_t)s * OUTC + c);
    }
    if (r0 + 2 < r1) sC = csr[r0 + 2];
    if (r0 + 3 < r1) sD = csr[r0 + 3];

    int k = r0;
    for (; k + 1 < r1; k += 2) {
        float vcA = vA, vcB = vB;
        H4 hcA = hA, hcB = hB;
        int sE = (k + 4 < r1) ? csr[k + 4] : 0;
        int sF = (k + 5 < r1) ? csr[k + 5] : 0;
        if (k + 2 < r1) {
            float t = als[sC] + aldn;
            vA = fmaxf(t, NEG * t);
            hA.u = *(const ushort4*)(h2 + (size_t)sC * OUTC + c);
        }
        if (k + 3 < r1) {
            float t = als[sD] + aldn;
            vB = fmaxf(t, NEG * t);
            hB.u = *(const ushort4*)(h2 + (size_t)sD * OUTC + c);
        }
        sC = sE; sD = sF;
        float wA = __expf(vcA), wB = __expf(vcB);
        sum += wA + wB;
        a0 = fmaf(wA, __half2float(hcA.h[0]), a0); a0 = fmaf(wB, __half2float(hcB.h[0]), a0);
        a1 = fmaf(wA, __half2float(hcA.h[1]), a1); a1 = fmaf(wB, __half2float(hcB.h[1]), a1);
        a2 = fmaf(wA, __half2float(hcA.h[2]), a2); a2 = fmaf(wB, __half2float(hcB.h[2]), a2);
        a3 = fmaf(wA, __half2float(hcA.h[3]), a3); a3 = fmaf(wB, __half2float(hcB.h[3]), a3);
    }
    if (k < r1) {
        float wA = __expf(vA);
        sum += wA;
        a0 = fmaf(wA, __half2float(hA.h[0]), a0);
        a1 = fmaf(wA, __half2float(hA.h[1]), a1);
        a2 = fmaf(wA, __half2float(hA.h[2]), a2);
        a3 = fmaf(wA, __half2float(hA.h[3]), a3);
    }

    float inv = 1.0f / sum;
    float4 bv = *(const float4*)(b2 + c);
    float4 o;
    o.x = a0 * inv + bv.x; o.y = a1 * inv + bv.y;
    o.z = a2 * inv + bv.z; o.w = a3 * inv + bv.w;
    *(float4*)(out + (size_t)n * OUTC + c) = o;
}

extern "C" void kernel_launch(void* const* d_in, const int* in_sizes, int n_in,
                              void* d_out, int out_size, void* d_ws, size_t ws_size,
                              hipStream_t stream)
{
    const float* x   = (const float*)d_in[0];
    const int*   ei  = (const int*)  d_in[1];
    const float* W1  = (const float*)d_in[2];
    const float* as1 = (const float*)d_in[3];
    const float* ad1 = (const float*)d_in[4];
    const float* b1  = (const float*)d_in[5];
    const float* W2  = (const float*)d_in[6];
    const float* as2 = (const float*)d_in[7];
    const float* ad2 = (const float*)d_in[8];
    const float* b2  = (const float*)d_in[9];
    float* out = (float*)d_out;

    char* wsb = (char*)d_ws;
    const size_t SZ_H1 = (size_t)N_NODES * F1 * sizeof(__half);   // 12.8 MB
    __half* h1h = (__half*)wsb;
    __half* h1b = (__half*)(wsb + SZ_H1);
    float*  als1 = (float*)(wsb + 2 * SZ_H1);                     // N*8
    float*  ald1 = als1 + (size_t)N_NODES * 8;                    // N*8
    __half* h2f  = (__half*)(ald1 + (size_t)N_NODES * 8);         // N*16 fp16
    float*  als2 = (float*)(h2f + (size_t)N_NODES * OUTC);        // N
    float*  ald2 = als2 + N_NODES;                                // N
    __half* w1t  = (__half*)(ald2 + N_NODES);                     // 128*128 fp16
    __half* waT  = w1t + INC * F1;                                // 16*128 fp16
    int*    tmp  = (int*)(waT + 16 * INC);                        // NE ints (packed)
    int*    cnt  = tmp + NE;                                      // NBKT*NPART
    int*    csr  = cnt + NBKT * NPART;                            // NE
    int*    rowstart = csr + NE;                                  // N+1
    int*    dcnt = rowstart + N_NODES + 1;                        // 64*NBKT
    int*    perm = dcnt + 64 * NBKT;                              // N

    // ---- CSR build + weight prep + degree-sorted permutation ----
    part_hist   <<<NPART, 256, 0, stream>>>(ei, cnt);
    w1t_kernel  <<<72, 256, 0, stream>>>(W1, as1, ad1, w1t, waT);
    scan25k     <<<1, 1024, 0, stream>>>(cnt);
    part_scatter<<<NPART, 256, 0, stream>>>(ei, cnt, tmp);
    bucket_sort <<<NBKT, 256, 0, stream>>>(tmp, cnt, rowstart, csr, dcnt);
    scan12k     <<<1, 1024, 0, stream>>>(dcnt);
    dscatter    <<<NBKT, 256, 0, stream>>>(rowstart, dcnt, perm);

    // ---- layer 1 ----
    node1_kernel<<<(N_NODES + 63) / 64, 256, 0, stream>>>(x, w1t, waT, h1h, als1, ald1);
    agg1_kernel<<<N_NODES / 16, 256, 0, stream>>>(rowstart, csr, perm, h1h, als1, ald1, b1, h1b);

    // ---- layer 2 ----
    node2_kernel<<<(N_NODES + 255) / 256, 256, 0, stream>>>(h1b, W2, as2, ad2, h2f, als2, ald2);
    agg2_kernel<<<(N_NODES + 63) / 64, 256, 0, stream>>>(rowstart, csr, perm, h2f, als2, ald2, b2, out);
}

// Round 15
// 232.986 us; speedup vs baseline: 1.5902x; 1.0992x over previous
//
#include <hip/hip_runtime.h>
#include <hip/hip_fp16.h>
#include <math.h>

#define N_NODES 50000
#define NE      800000
#define INC     128
#define F1      128     // HEADS*HID
#define HEADS   8
#define HID     16
#define OUTC    16
#define NEG     0.2f
#define NBKT    196      // (N_NODES+255)>>8
#define NPART   128      // partition blocks

union H4 { ushort4 u; __half h[4]; };
union H8 { uint4 u; __half h[8]; };

typedef _Float16 f16x8 __attribute__((ext_vector_type(8)));
typedef float    f32x4 __attribute__((ext_vector_type(4)));

// ==== fused: per-block dst histogram (blocks 0..127) + weight prep (128..199)
__global__ __launch_bounds__(256) void prep_kernel(const int* __restrict__ ei,
                                                   int* __restrict__ cnt,
                                                   const float* __restrict__ W1,
                                                   const float* __restrict__ as1,
                                                   const float* __restrict__ ad1,
                                                   __half* __restrict__ W1t,
                                                   __half* __restrict__ waT) {
    __shared__ int h[NBKT];
    int b = blockIdx.x, tid = threadIdx.x;
    if (b < NPART) {                     // edge histogram by dst>>8
        for (int i = tid; i < NBKT; i += 256) h[i] = 0;
        __syncthreads();
        for (int e = b * 256 + tid; e < NE; e += NPART * 256)
            atomicAdd(&h[ei[NE + e] >> 8], 1);
        __syncthreads();
        for (int i = tid; i < NBKT; i += 256) cnt[i * NPART + b] = h[i];
    } else if (b < NPART + 64) {         // W1 transpose to fp16
        int i = (b - NPART) * 256 + tid;
        int k = i >> 7, nn = i & 127;
        W1t[nn * 128 + k] = __float2half(W1[k * 128 + nn]);
    } else {                             // folded attention matrix Wa
        int i = (b - NPART - 64) * 256 + tid;   // 0..2047
        int col = i & 15, k = i >> 4;
        int hh = col & 7;
        const float* av = (col < 8) ? as1 : ad1;
        float s = 0.f;
        #pragma unroll
        for (int cc = 0; cc < 16; ++cc)
            s += W1[k * 128 + hh * 16 + cc] * av[hh * 16 + cc];
        waT[col * 128 + k] = __float2half(s);   // B-frag layout [n=col][k]
    }
}

__global__ __launch_bounds__(1024) void scan25k(int* __restrict__ cnt) {
    __shared__ int part[1024];
    const int TOT = NBKT * NPART;             // 25088
    const int PER = (TOT + 1023) / 1024;      // 25
    int tid = threadIdx.x;
    int base = tid * PER;
    int s = 0;
    for (int i = 0; i < PER; ++i) {
        int idx = base + i;
        if (idx < TOT) s += cnt[idx];
    }
    part[tid] = s; __syncthreads();
    for (int off = 1; off < 1024; off <<= 1) {
        int t = (tid >= off) ? part[tid - off] : 0;
        __syncthreads();
        part[tid] += t;
        __syncthreads();
    }
    int run = part[tid] - s;
    for (int i = 0; i < PER; ++i) {
        int idx = base + i;
        if (idx < TOT) { int v = cnt[idx]; cnt[idx] = run; run += v; }
    }
}

// tmp packing: s in bits 0..15 (N<65536), d&255 in bits 16..23
__global__ __launch_bounds__(256) void part_scatter(const int* __restrict__ ei,
                                                    const int* __restrict__ cnt,
                                                    int* __restrict__ tmp) {
    __shared__ int cur[NBKT];
    int tid = threadIdx.x;
    for (int i = tid; i < NBKT; i += 256) cur[i] = cnt[i * NPART + blockIdx.x];
    __syncthreads();
    for (int e = blockIdx.x * 256 + tid; e < NE; e += NPART * 256) {
        int s = ei[e], d = ei[NE + e];
        int p = atomicAdd(&cur[d >> 8], 1);
        tmp[p] = s | ((d & 255) << 16);
    }
}

__global__ __launch_bounds__(256) void bucket_sort(const int* __restrict__ tmp,
                                                   const int* __restrict__ cnt,
                                                   int* __restrict__ rowstart,
                                                   int* __restrict__ csr) {
    __shared__ int h[256];
    int b = blockIdx.x, tid = threadIdx.x;
    int base = cnt[b * NPART];
    int end  = (b == NBKT - 1) ? NE : cnt[(b + 1) * NPART];
    h[tid] = 0; __syncthreads();
    for (int i = base + tid; i < end; i += 256)
        atomicAdd(&h[(tmp[i] >> 16) & 255], 1);
    __syncthreads();
    int v = h[tid];
    for (int off = 1; off < 256; off <<= 1) {
        int t = (tid >= off) ? h[tid - off] : 0;
        __syncthreads();
        h[tid] += t;
        __syncthreads();
    }
    int excl = h[tid] - v;
    int n = (b << 8) + tid;
    if (n <= N_NODES) rowstart[n] = base + excl;
    __syncthreads();
    h[tid] = excl;
    __syncthreads();
    for (int i = base + tid; i < end; i += 256) {
        int e = tmp[i];
        int p = base + atomicAdd(&h[(e >> 16) & 255], 1);
        csr[p] = e & 0xFFFF;
    }
}

// ---------------- Layer 1: MFMA GEMM (x @ W1) + logits via Wa-GEMM ---------
__global__ __launch_bounds__(256) void node1_kernel(
    const float* __restrict__ x, const __half* __restrict__ W1t,
    const __half* __restrict__ waT,
    __half* __restrict__ hfeat, float* __restrict__ als, float* __restrict__ ald)
{
    __shared__ _Float16 Xh[64 * 136];    // 17.4 KB
    __shared__ _Float16 Wt[128 * 136];   // 34.8 KB (pad 8 halves/row)
    int tid = threadIdx.x;
    int n0 = blockIdx.x * 64;

    for (int idx = tid; idx < 128 * 16; idx += 256) {   // 16 x uint4 per row
        int row = idx >> 4, c8 = (idx & 15) * 8;
        *(uint4*)(&Wt[row * 136 + c8]) = ((const uint4*)W1t)[idx];
    }
    for (int idx = tid; idx < 64 * 32; idx += 256) {
        int m = idx >> 5, f4 = idx & 31;
        int n = n0 + m;
        float4 v = (n < N_NODES) ? ((const float4*)(x + (size_t)n * INC))[f4]
                                 : make_float4(0.f, 0.f, 0.f, 0.f);
        union { unsigned long long u; _Float16 h[4]; } p;
        p.h[0] = (_Float16)v.x; p.h[1] = (_Float16)v.y;
        p.h[2] = (_Float16)v.z; p.h[3] = (_Float16)v.w;
        *(unsigned long long*)(&Xh[m * 136 + f4 * 4]) = p.u;
    }
    __syncthreads();

    int wave = tid >> 6, lane = tid & 63;
    int colL = lane & 15, q = lane >> 4;
    int nb = wave * 32;

    f32x4 acc[4][2];
    #pragma unroll
    for (int mt = 0; mt < 4; ++mt)
        #pragma unroll
        for (int nt = 0; nt < 2; ++nt)
            acc[mt][nt] = (f32x4){0.f, 0.f, 0.f, 0.f};
    f32x4 acc2 = (f32x4){0.f, 0.f, 0.f, 0.f};   // logits, mt = wave

    #pragma unroll
    for (int kb = 0; kb < 4; ++kb) {
        int ko = kb * 32 + q * 8;
        f16x8 b0 = *(const f16x8*)(&Wt[(nb +  0 + colL) * 136 + ko]);
        f16x8 b1 = *(const f16x8*)(&Wt[(nb + 16 + colL) * 136 + ko]);
        #pragma unroll
        for (int mt = 0; mt < 4; ++mt) {
            f16x8 a = *(const f16x8*)(&Xh[(mt * 16 + colL) * 136 + ko]);
            acc[mt][0] = __builtin_amdgcn_mfma_f32_16x16x32_f16(a, b0, acc[mt][0], 0, 0, 0);
            acc[mt][1] = __builtin_amdgcn_mfma_f32_16x16x32_f16(a, b1, acc[mt][1], 0, 0, 0);
        }
        f16x8 bw = *(const f16x8*)(waT + colL * 128 + ko);           // global, L2-hot
        f16x8 aw = *(const f16x8*)(&Xh[(wave * 16 + colL) * 136 + ko]);
        acc2 = __builtin_amdgcn_mfma_f32_16x16x32_f16(aw, bw, acc2, 0, 0, 0);
    }

    // h stores (fp16)
    #pragma unroll
    for (int nt = 0; nt < 2; ++nt) {
        int col = nb + nt * 16 + colL;
        #pragma unroll
        for (int mt = 0; mt < 4; ++mt) {
            f32x4 d = acc[mt][nt];
            #pragma unroll
            for (int r = 0; r < 4; ++r) {
                int node = n0 + mt * 16 + q * 4 + r;
                if (node < N_NODES) hfeat[(size_t)node * F1 + col] = __float2half(d[r]);
            }
        }
    }
    // logit stores: split src/dst arrays (32B/node granularity for the gather)
    #pragma unroll
    for (int r = 0; r < 4; ++r) {
        int node = n0 + wave * 16 + q * 4 + r;
        if (node < N_NODES) {
            if (colL < 8) als[node * 8 + colL] = acc2[r];
            else          ald[node * 8 + (colL - 8)] = acc2[r];
        }
    }
}

// ------ Layer 1 gather: 16 lanes/node, 8 fp16/lane, depth-2 static pipeline -
__global__ __launch_bounds__(256) void agg1_kernel(
    const int* __restrict__ rowstart, const int* __restrict__ csr,
    const __half* __restrict__ h1, const float* __restrict__ als,
    const float* __restrict__ ald, const float* __restrict__ b1,
    __half* __restrict__ hout)
{
    int tid = threadIdx.x;
    int n = blockIdx.x * 16 + (tid >> 4);
    int lane = tid & 15;
    int c = lane * 8;
    int head = lane >> 1;
    float aldn = ald[n * 8 + head];
    float v0 = als[n * 8 + head] + aldn;
    v0 = fmaxf(v0, NEG * v0);
    float w0 = __expf(v0);
    float sum = w0;
    float a[8];
    {
        H8 hs; hs.u = *(const uint4*)(h1 + (size_t)n * F1 + c);
        #pragma unroll
        for (int i = 0; i < 8; ++i) a[i] = w0 * __half2float(hs.h[i]);
    }
    int r0 = rowstart[n], r1 = rowstart[n + 1];

    float vA = 0.f, vB = 0.f;
    H8 hA, hB; hA.u = make_uint4(0,0,0,0); hB.u = hA.u;
    int sC = 0, sD = 0;
    if (r0 < r1) {
        int s = csr[r0];
        float t = als[s * 8 + head] + aldn;
        vA = fmaxf(t, NEG * t);
        hA.u = *(const uint4*)(h1 + (size_t)s * F1 + c);
    }
    if (r0 + 1 < r1) {
        int s = csr[r0 + 1];
        float t = als[s * 8 + head] + aldn;
        vB = fmaxf(t, NEG * t);
        hB.u = *(const uint4*)(h1 + (size_t)s * F1 + c);
    }
    if (r0 + 2 < r1) sC = csr[r0 + 2];
    if (r0 + 3 < r1) sD = csr[r0 + 3];

    int k = r0;
    for (; k + 1 < r1; k += 2) {
        float vcA = vA, vcB = vB;
        H8 hcA = hA, hcB = hB;
        int sE = (k + 4 < r1) ? csr[k + 4] : 0;
        int sF = (k + 5 < r1) ? csr[k + 5] : 0;
        if (k + 2 < r1) {
            float t = als[sC * 8 + head] + aldn;
            vA = fmaxf(t, NEG * t);
            hA.u = *(const uint4*)(h1 + (size_t)sC * F1 + c);
        }
        if (k + 3 < r1) {
            float t = als[sD * 8 + head] + aldn;
            vB = fmaxf(t, NEG * t);
            hB.u = *(const uint4*)(h1 + (size_t)sD * F1 + c);
        }
        sC = sE; sD = sF;
        float wA = __expf(vcA), wB = __expf(vcB);
        sum += wA + wB;
        #pragma unroll
        for (int i = 0; i < 8; ++i) {
            a[i] = fmaf(wA, __half2float(hcA.h[i]), a[i]);
            a[i] = fmaf(wB, __half2float(hcB.h[i]), a[i]);
        }
    }
    if (k < r1) {                      // odd tail: consume slot A
        float wA = __expf(vA);
        sum += wA;
        #pragma unroll
        for (int i = 0; i < 8; ++i) a[i] = fmaf(wA, __half2float(hA.h[i]), a[i]);
    }

    float inv = 1.0f / sum;
    H8 t;
    #pragma unroll
    for (int i = 0; i < 8; ++i) {
        float o = a[i] * inv + b1[c + i];
        o = o > 0.f ? o : (__expf(o) - 1.0f);
        t.h[i] = __float2half(o);
    }
    *(uint4*)(hout + (size_t)n * F1 + c) = t.u;
}

// ---------------- Layer 2: GEMM (h1' @ W2) + logits, fp16 in/out ----------
__global__ __launch_bounds__(256) void node2_kernel(
    const __half* __restrict__ h1, const float* __restrict__ W2,
    const float* __restrict__ a_s, const float* __restrict__ a_d,
    __half* __restrict__ h2, float* __restrict__ als2, float* __restrict__ ald2)
{
    __shared__ float W2l[F1 * OUTC];   // 8 KB
    for (int i = threadIdx.x; i < F1 * OUTC; i += 256) W2l[i] = W2[i];
    __syncthreads();
    int n = blockIdx.x * blockDim.x + threadIdx.x;
    if (n >= N_NODES) return;

    float o[OUTC];
    #pragma unroll
    for (int c = 0; c < OUTC; ++c) o[c] = 0.f;
    const uint4* xr = (const uint4*)(h1 + (size_t)n * F1);
    for (int k8 = 0; k8 < 16; ++k8) {
        H8 xv; xv.u = xr[k8];
        int k = k8 * 8;
        #pragma unroll
        for (int j = 0; j < 8; ++j) {
            float xf = __half2float(xv.h[j]);
            #pragma unroll
            for (int c = 0; c < OUTC; ++c)
                o[c] = fmaf(xf, W2l[(k + j) * OUTC + c], o[c]);
        }
    }
    H8 s0, s1;
    #pragma unroll
    for (int j = 0; j < 8; ++j) { s0.h[j] = __float2half(o[j]); s1.h[j] = __float2half(o[8 + j]); }
    uint4* h2o = (uint4*)(h2 + (size_t)n * OUTC);
    h2o[0] = s0.u; h2o[1] = s1.u;
    float ps = 0.f, pd = 0.f;
    #pragma unroll
    for (int c = 0; c < OUTC; ++c) { ps += o[c] * a_s[c]; pd += o[c] * a_d[c]; }
    als2[n] = ps; ald2[n] = pd;
}

// ------ Layer 2 gather: 4 lanes/node, 4 fp16/lane, depth-2 static pipeline -
__global__ __launch_bounds__(256) void agg2_kernel(
    const int* __restrict__ rowstart, const int* __restrict__ csr,
    const __half* __restrict__ h2, const float* __restrict__ als,
    const float* __restrict__ ald, const float* __restrict__ b2,
    float* __restrict__ out)
{
    int tid = threadIdx.x;
    int n = blockIdx.x * 64 + (tid >> 2);
    if (n >= N_NODES) return;
    int c = (tid & 3) * 4;
    float aldn = ald[n];
    float v0 = als[n] + aldn;
    v0 = fmaxf(v0, NEG * v0);
    float w0 = __expf(v0);
    float sum = w0;
    H4 hs; hs.u = *(const ushort4*)(h2 + (size_t)n * OUTC + c);
    float a0 = w0 * __half2float(hs.h[0]), a1 = w0 * __half2float(hs.h[1]);
    float a2 = w0 * __half2float(hs.h[2]), a3 = w0 * __half2float(hs.h[3]);
    int r0 = rowstart[n], r1 = rowstart[n + 1];

    float vA = 0.f, vB = 0.f;
    H4 hA, hB; hA.u = make_ushort4(0,0,0,0); hB.u = hA.u;
    int sC = 0, sD = 0;
    if (r0 < r1) {
        int s = csr[r0];
        float t = als[s] + aldn;
        vA = fmaxf(t, NEG * t);
        hA.u = *(const ushort4*)(h2 + (size_t)s * OUTC + c);
    }
    if (r0 + 1 < r1) {
        int s = csr[r0 + 1];
        float t = als[s] + aldn;
        vB = fmaxf(t, NEG * t);
        hB.u = *(const ushort4*)(h2 + (size_t)s * OUTC + c);
    }
    if (r0 + 2 < r1) sC = csr[r0 + 2];
    if (r0 + 3 < r1) sD = csr[r0 + 3];

    int k = r0;
    for (; k + 1 < r1; k += 2) {
        float vcA = vA, vcB = vB;
        H4 hcA = hA, hcB = hB;
        int sE = (k + 4 < r1) ? csr[k + 4] : 0;
        int sF = (k + 5 < r1) ? csr[k + 5] : 0;
        if (k + 2 < r1) {
            float t = als[sC] + aldn;
            vA = fmaxf(t, NEG * t);
            hA.u = *(const ushort4*)(h2 + (size_t)sC * OUTC + c);
        }
        if (k + 3 < r1) {
            float t = als[sD] + aldn;
            vB = fmaxf(t, NEG * t);
            hB.u = *(const ushort4*)(h2 + (size_t)sD * OUTC + c);
        }
        sC = sE; sD = sF;
        float wA = __expf(vcA), wB = __expf(vcB);
        sum += wA + wB;
        a0 = fmaf(wA, __half2float(hcA.h[0]), a0); a0 = fmaf(wB, __half2float(hcB.h[0]), a0);
        a1 = fmaf(wA, __half2float(hcA.h[1]), a1); a1 = fmaf(wB, __half2float(hcB.h[1]), a1);
        a2 = fmaf(wA, __half2float(hcA.h[2]), a2); a2 = fmaf(wB, __half2float(hcB.h[2]), a2);
        a3 = fmaf(wA, __half2float(hcA.h[3]), a3); a3 = fmaf(wB, __half2float(hcB.h[3]), a3);
    }
    if (k < r1) {
        float wA = __expf(vA);
        sum += wA;
        a0 = fmaf(wA, __half2float(hA.h[0]), a0);
        a1 = fmaf(wA, __half2float(hA.h[1]), a1);
        a2 = fmaf(wA, __half2float(hA.h[2]), a2);
        a3 = fmaf(wA, __half2float(hA.h[3]), a3);
    }

    float inv = 1.0f / sum;
    float4 bv = *(const float4*)(b2 + c);
    float4 o;
    o.x = a0 * inv + bv.x; o.y = a1 * inv + bv.y;
    o.z = a2 * inv + bv.z; o.w = a3 * inv + bv.w;
    *(float4*)(out + (size_t)n * OUTC + c) = o;
}

extern "C" void kernel_launch(void* const* d_in, const int* in_sizes, int n_in,
                              void* d_out, int out_size, void* d_ws, size_t ws_size,
                              hipStream_t stream)
{
    const float* x   = (const float*)d_in[0];
    const int*   ei  = (const int*)  d_in[1];
    const float* W1  = (const float*)d_in[2];
    const float* as1 = (const float*)d_in[3];
    const float* ad1 = (const float*)d_in[4];
    const float* b1  = (const float*)d_in[5];
    const float* W2  = (const float*)d_in[6];
    const float* as2 = (const float*)d_in[7];
    const float* ad2 = (const float*)d_in[8];
    const float* b2  = (const float*)d_in[9];
    float* out = (float*)d_out;

    char* wsb = (char*)d_ws;
    const size_t SZ_H1 = (size_t)N_NODES * F1 * sizeof(__half);   // 12.8 MB
    __half* h1h = (__half*)wsb;
    __half* h1b = (__half*)(wsb + SZ_H1);
    float*  als1 = (float*)(wsb + 2 * SZ_H1);                     // N*8
    float*  ald1 = als1 + (size_t)N_NODES * 8;                    // N*8
    __half* h2f  = (__half*)(ald1 + (size_t)N_NODES * 8);         // N*16 fp16
    float*  als2 = (float*)(h2f + (size_t)N_NODES * OUTC);        // N
    float*  ald2 = als2 + N_NODES;                                // N
    __half* w1t  = (__half*)(ald2 + N_NODES);                     // 128*128 fp16
    __half* waT  = w1t + INC * F1;                                // 16*128 fp16
    int*    tmp  = (int*)(waT + 16 * INC);                        // NE ints (packed)
    int*    cnt  = tmp + NE;                                      // NBKT*NPART
    int*    csr  = cnt + NBKT * NPART;                            // NE
    int*    rowstart = csr + NE;                                  // N+1

    // ---- CSR build + weight prep (fused first dispatch) ----
    prep_kernel <<<NPART + 72, 256, 0, stream>>>(ei, cnt, W1, as1, ad1, w1t, waT);
    scan25k     <<<1, 1024, 0, stream>>>(cnt);
    part_scatter<<<NPART, 256, 0, stream>>>(ei, cnt, tmp);
    bucket_sort <<<NBKT, 256, 0, stream>>>(tmp, cnt, rowstart, csr);

    // ---- layer 1 ----
    node1_kernel<<<(N_NODES + 63) / 64, 256, 0, stream>>>(x, w1t, waT, h1h, als1, ald1);
    agg1_kernel<<<N_NODES / 16, 256, 0, stream>>>(rowstart, csr, h1h, als1, ald1, b1, h1b);

    // ---- layer 2 ----
    node2_kernel<<<(N_NODES + 255) / 256, 256, 0, stream>>>(h1b, W2, as2, ad2, h2f, als2, ald2);
    agg2_kernel<<<(N_NODES + 63) / 64, 256, 0, stream>>>(rowstart, csr, h2f, als2, ald2, b2, out);
}